// Round 2
// baseline (674.642 us; speedup 1.0000x reference)
//
#include <hip/hip_runtime.h>

typedef unsigned short u16;
typedef unsigned int u32;

#define E_EDGES 600000
#define NUM_FINE 50000
#define NUM_COARSE 12500
#define FINE_BLOCKS 391   // ceil(50000/128)
#define COARSE_BLOCKS 98  // ceil(12500/128)
#define SMAX 24           // max segments (distinct fine nodes) per 128-edge tile

typedef __attribute__((ext_vector_type(8))) short short8;
typedef __attribute__((ext_vector_type(4))) float f32x4;

union Frag { short8 v; u16 s[8]; u32 u[4]; uint4 q; };

__device__ __forceinline__ u32 rne_bf16(float f) {
  union { float f; u32 u; } v; v.f = f;
  return (v.u + 0x7FFFu + ((v.u >> 16) & 1u)) >> 16;
}
__device__ __forceinline__ float bf2f(u32 bits16) {
  union { u32 u; float f; } v; v.u = bits16 << 16; return v.f;
}
__device__ __forceinline__ u32 addrelu_pack(u32 a, u32 b) {
  float lo = fmaxf(bf2f(a & 0xFFFFu) + bf2f(b & 0xFFFFu), 0.0f);
  float hi = fmaxf(bf2f(a >> 16) + bf2f(b >> 16), 0.0f);
  return rne_bf16(lo) | (rne_bf16(hi) << 16);
}

// ---------------------------------------------------------------------------
// convert_w: build fragment-ordered bf16 copies of W1 (fine and coarse K-order)
// and W2. Layout: [ks][nt][lane][j], value = W[k = ks*32+(lane>>4)*8+j]
//                                             [n = nt*16+(lane&15)].
// ---------------------------------------------------------------------------
__global__ void convert_w(const float* __restrict__ W1, const float* __restrict__ W2,
                          u16* __restrict__ BW1f, u16* __restrict__ BW1c,
                          u16* __restrict__ BW2) {
  int o = blockIdx.x * 256 + threadIdx.x;
  if (o >= 81920) return;
  int which = (o < 32768) ? 0 : (o < 65536 ? 1 : 2);
  int idx = (which == 2) ? (o - 65536) : (o & 32767);
  int j = idx & 7, lane = (idx >> 3) & 63, nt = (idx >> 9) & 7, ks = idx >> 12;
  int k = ks * 32 + (lane >> 4) * 8 + j;
  int n = nt * 16 + (lane & 15);
  float v;
  if (which == 2) v = W2[k * 128 + n];
  else {
    int row;
    if (which == 0) row = (k < 128) ? k : (256 + (k - 128));          // si | di
    else            row = (k < 128) ? (128 + k) : (384 + (k - 128));  // sk | dk
    v = W1[row * 128 + n];
  }
  u16 b = (u16)rne_bf16(v);
  if (which == 0) BW1f[idx] = b; else if (which == 1) BW1c[idx] = b; else BW2[idx] = b;
}

// ---------------------------------------------------------------------------
// Counting sort of edges by fine_idx
// ---------------------------------------------------------------------------
__global__ void count_kernel(const int* __restrict__ fidx, int* __restrict__ cnt) {
  int e = blockIdx.x * 256 + threadIdx.x;
  if (e < E_EDGES) atomicAdd(&cnt[fidx[e]], 1);
}

__global__ void scan_kernel(const int* __restrict__ cnt, int* __restrict__ wcur) {
  __shared__ int wsum[16], woff[16];
  __shared__ int runningS, chunkTot;
  int tid = threadIdx.x, lane = tid & 63, w = tid >> 6;
  if (tid == 0) runningS = 0;
  __syncthreads();
  for (int base = 0; base < NUM_FINE; base += 1024) {
    int i = base + tid;
    int v = (i < NUM_FINE) ? cnt[i] : 0;
    int x = v;
#pragma unroll
    for (int off = 1; off < 64; off <<= 1) {
      int y = __shfl_up(x, off, 64);
      if (lane >= off) x += y;
    }
    if (lane == 63) wsum[w] = x;
    __syncthreads();
    if (tid == 0) {
      int a = 0;
      for (int k = 0; k < 16; ++k) { int t = wsum[k]; woff[k] = a; a += t; }
      chunkTot = a;
    }
    __syncthreads();
    int run = runningS;
    if (i < NUM_FINE) wcur[i] = run + woff[w] + x - v;  // exclusive scan
    __syncthreads();
    if (tid == 0) runningS += chunkTot;
    __syncthreads();
  }
}

__global__ void scatter_kernel(const int* __restrict__ fidx, const int* __restrict__ cidx,
                               int* __restrict__ wcur, u32* __restrict__ spk) {
  int e = blockIdx.x * 256 + threadIdx.x;
  if (e < E_EDGES) {
    int fi = fidx[e];
    int p = atomicAdd(&wcur[fi], 1);
    spk[p] = ((u32)fi << 14) | (u32)cidx[e];  // fi<2^16, ci<2^14
  }
}

// ---------------------------------------------------------------------------
// precompute: P_fine / P_coarse (bf16). B-fragments read straight from global
// (L2-broadcast across blocks) — no LDS, no barrier.
// ---------------------------------------------------------------------------
__global__ __launch_bounds__(256, 2) void precompute_kernel(
    const float* __restrict__ h_dk_coarse, const float* __restrict__ h_si_fine,
    const float* __restrict__ h_sk_coarse, const float* __restrict__ h_di_fine,
    const u16* __restrict__ BW1f, const u16* __restrict__ BW1c,
    const float* __restrict__ b1, u16* __restrict__ Pf, u16* __restrict__ Pc) {
  const int b = blockIdx.x;
  const bool fine = b < FINE_BLOCKS;
  const int rowStart = fine ? b * 128 : (b - FINE_BLOCKS) * 128;
  const int R = fine ? NUM_FINE : NUM_COARSE;
  const float* __restrict__ X1 = fine ? h_si_fine : h_sk_coarse;
  const float* __restrict__ X2 = fine ? h_di_fine : h_dk_coarse;
  const u16* __restrict__ BW = fine ? BW1f : BW1c;
  u16* __restrict__ P = fine ? Pf : Pc;

  const int tid = threadIdx.x;
  const int lane = tid & 63;
  const int w = tid >> 6;
  const int qd = lane >> 4;
  const int ml = lane & 15;

  int rowA[2]; bool vA[2];
#pragma unroll
  for (int mt = 0; mt < 2; ++mt) {
    rowA[mt] = rowStart + w * 32 + mt * 16 + ml;
    vA[mt] = rowA[mt] < R;
  }

  f32x4 acc[2][8];
#pragma unroll
  for (int mt = 0; mt < 2; ++mt)
#pragma unroll
    for (int nt = 0; nt < 8; ++nt) acc[mt][nt] = (f32x4){0.f, 0.f, 0.f, 0.f};

  for (int ks = 0; ks < 8; ++ks) {
    const int k0 = ks * 32 + qd * 8;  // 0..255
    short8 a[2];
#pragma unroll
    for (int mt = 0; mt < 2; ++mt) {
      Frag af;
      if (vA[mt]) {
        const float* src = (k0 < 128) ? (X1 + rowA[mt] * 128 + k0)
                                      : (X2 + rowA[mt] * 128 + (k0 - 128));
        const float4* s4 = (const float4*)src;
        float4 v0 = s4[0], v1 = s4[1];
        af.u[0] = rne_bf16(v0.x) | (rne_bf16(v0.y) << 16);
        af.u[1] = rne_bf16(v0.z) | (rne_bf16(v0.w) << 16);
        af.u[2] = rne_bf16(v1.x) | (rne_bf16(v1.y) << 16);
        af.u[3] = rne_bf16(v1.z) | (rne_bf16(v1.w) << 16);
      } else {
        af.u[0] = af.u[1] = af.u[2] = af.u[3] = 0u;
      }
      a[mt] = af.v;
    }
#pragma unroll
    for (int nt = 0; nt < 8; ++nt) {
      Frag bfr;
      bfr.q = *(const uint4*)(BW + (((ks * 8 + nt) * 64) + lane) * 8);
      acc[0][nt] = __builtin_amdgcn_mfma_f32_16x16x32_bf16(a[0], bfr.v, acc[0][nt], 0, 0, 0);
      acc[1][nt] = __builtin_amdgcn_mfma_f32_16x16x32_bf16(a[1], bfr.v, acc[1][nt], 0, 0, 0);
    }
  }

  float b1v[8];
#pragma unroll
  for (int nt = 0; nt < 8; ++nt) b1v[nt] = fine ? 0.0f : b1[nt * 16 + ml];

#pragma unroll
  for (int mt = 0; mt < 2; ++mt) {
#pragma unroll
    for (int r = 0; r < 4; ++r) {
      const int row = rowStart + w * 32 + mt * 16 + qd * 4 + r;
      if (row < R) {
#pragma unroll
        for (int nt = 0; nt < 8; ++nt) {
          P[row * 128 + nt * 16 + ml] = (u16)rne_bf16(acc[mt][nt][r] + b1v[nt]);
        }
      }
    }
  }
}

// ---------------------------------------------------------------------------
// edge_kernel: 128 SORTED edges per block. MFMA psi, then LDS segment-sum by
// fine node; plain store for interior nodes, atomicAdd only at tile boundaries.
// ---------------------------------------------------------------------------
__global__ __launch_bounds__(256, 4) void edge_kernel(
    const u16* __restrict__ Pf, const u16* __restrict__ Pc,
    const u16* __restrict__ BW2, const float* __restrict__ hdk,
    const u32* __restrict__ spk, const float* __restrict__ b2,
    float* __restrict__ out) {
  __shared__ float lacc[SMAX * 128];
  __shared__ int sh_fi[128], sh_ci[128], sh_segid[128], sh_segfi[SMAX];
  __shared__ int shS, shHead, shTail, shW0tot;

  const int tid = threadIdx.x;
  const int eb = blockIdx.x * 128;
  const int V = min(128, E_EDGES - eb);

  if (tid < 128) {
    if (tid < V) {
      u32 p = spk[eb + tid];
      sh_fi[tid] = (int)(p >> 14);
      sh_ci[tid] = (int)(p & 16383u);
    } else { sh_fi[tid] = -1; sh_ci[tid] = 0; }
  }
  for (int i = tid; i < SMAX * 128; i += 256) lacc[i] = 0.f;
  if (tid == 0) {
    shHead = (eb > 0) ? (int)(spk[eb - 1] >> 14) : -1;
    shTail = (eb + V < E_EDGES) ? (int)(spk[eb + V] >> 14) : -1;
  }
  __syncthreads();

  // segment-id scan over the 128 rows (2 waves)
  int f = 0, x = 0;
  if (tid < 128) {
    f = (tid < V) ? ((tid == 0) ? 1 : (sh_fi[tid] != sh_fi[tid - 1] ? 1 : 0)) : 0;
    x = f;
#pragma unroll
    for (int off = 1; off < 64; off <<= 1) {
      int y = __shfl_up(x, off, 64);
      if ((tid & 63) >= off) x += y;
    }
  }
  if (tid == 63) shW0tot = x;
  __syncthreads();
  if (tid >= 64 && tid < 128) x += shW0tot;
  if (tid < 128) {
    int sg = x - 1;
    sh_segid[tid] = sg;
    if (f && sg < SMAX) sh_segfi[sg] = sh_fi[tid];
  }
  if (tid == V - 1) shS = x;
  __syncthreads();

  const int S = shS;
  const bool fallback = (S > SMAX);

  const int lane = tid & 63;
  const int w = tid >> 6;
  const int qd = lane >> 4;
  const int ml = lane & 15;

  int fiA[2], ciA[2]; bool vA[2];
#pragma unroll
  for (int mt = 0; mt < 2; ++mt) {
    const int lr = w * 32 + mt * 16 + ml;
    vA[mt] = lr < V;
    fiA[mt] = vA[mt] ? sh_fi[lr] : 0;
    ciA[mt] = vA[mt] ? sh_ci[lr] : 0;
  }

  f32x4 acc[2][8];
#pragma unroll
  for (int mt = 0; mt < 2; ++mt)
#pragma unroll
    for (int nt = 0; nt < 8; ++nt) acc[mt][nt] = (f32x4){0.f, 0.f, 0.f, 0.f};

  for (int ks = 0; ks < 4; ++ks) {
    const int k0 = ks * 32 + qd * 8;
    short8 a[2];
#pragma unroll
    for (int mt = 0; mt < 2; ++mt) {
      Frag af;
      if (vA[mt]) {
        uint4 pf = *(const uint4*)(Pf + fiA[mt] * 128 + k0);
        uint4 pc = *(const uint4*)(Pc + ciA[mt] * 128 + k0);
        af.u[0] = addrelu_pack(pf.x, pc.x);
        af.u[1] = addrelu_pack(pf.y, pc.y);
        af.u[2] = addrelu_pack(pf.z, pc.z);
        af.u[3] = addrelu_pack(pf.w, pc.w);
      } else {
        af.u[0] = af.u[1] = af.u[2] = af.u[3] = 0u;
      }
      a[mt] = af.v;
    }
#pragma unroll
    for (int nt = 0; nt < 8; ++nt) {
      Frag bfr;
      bfr.q = *(const uint4*)(BW2 + (((ks * 8 + nt) * 64) + lane) * 8);
      acc[0][nt] = __builtin_amdgcn_mfma_f32_16x16x32_bf16(a[0], bfr.v, acc[0][nt], 0, 0, 0);
      acc[1][nt] = __builtin_amdgcn_mfma_f32_16x16x32_bf16(a[1], bfr.v, acc[1][nt], 0, 0, 0);
    }
  }

  float b2v[8];
#pragma unroll
  for (int nt = 0; nt < 8; ++nt) b2v[nt] = b2[nt * 16 + ml];

#pragma unroll
  for (int mt = 0; mt < 2; ++mt) {
#pragma unroll
    for (int r = 0; r < 4; ++r) {
      const int lr = w * 32 + mt * 16 + qd * 4 + r;
      if (lr < V) {
        const float* __restrict__ hrow = hdk + sh_ci[lr] * 128;
        if (!fallback) {
          const int sg = sh_segid[lr];
#pragma unroll
          for (int nt = 0; nt < 8; ++nt) {
            const int col = nt * 16 + ml;
            const float psi = fmaxf(acc[mt][nt][r] + b2v[nt], 0.0f);
            atomicAdd(&lacc[sg * 128 + col], psi * hrow[col]);
          }
        } else {
          float* __restrict__ op = out + (size_t)sh_fi[lr] * 128;
#pragma unroll
          for (int nt = 0; nt < 8; ++nt) {
            const int col = nt * 16 + ml;
            const float psi = fmaxf(acc[mt][nt][r] + b2v[nt], 0.0f);
            atomicAdd(op + col, psi * hrow[col]);
          }
        }
      }
    }
  }
  __syncthreads();

  if (!fallback) {
    const int tot = S * 128;
    for (int idx = tid; idx < tot; idx += 256) {
      const int s = idx >> 7, col = idx & 127;
      const float v = lacc[idx];
      const int fi = sh_segfi[s];
      const bool at = (s == 0 && shHead == fi) || (s == S - 1 && shTail == fi);
      if (at) atomicAdd(&out[(size_t)fi * 128 + col], v);
      else out[(size_t)fi * 128 + col] = v;
    }
  }
}

extern "C" void kernel_launch(void* const* d_in, const int* in_sizes, int n_in,
                              void* d_out, int out_size, void* d_ws, size_t ws_size,
                              hipStream_t stream) {
  const float* h_dk = (const float*)d_in[0];
  const float* h_si = (const float*)d_in[1];
  const float* h_sk = (const float*)d_in[2];
  const float* h_di = (const float*)d_in[3];
  const int* fidx = (const int*)d_in[4];
  const int* cidx = (const int*)d_in[5];
  const float* W1 = (const float*)d_in[6];
  const float* b1 = (const float*)d_in[7];
  const float* W2 = (const float*)d_in[8];
  const float* b2 = (const float*)d_in[9];
  float* out = (float*)d_out;

  // workspace layout (≈18.1 MiB)
  u16* Pf   = (u16*)d_ws;                      // 50000*128 bf16
  u16* Pc   = Pf + (size_t)NUM_FINE * 128;     // 12500*128 bf16
  u16* BW1f = Pc + (size_t)NUM_COARSE * 128;   // 32768
  u16* BW1c = BW1f + 32768;                    // 32768
  u16* BW2  = BW1c + 32768;                    // 16384
  int* cnt  = (int*)(BW2 + 16384);             // 50000
  int* wcur = cnt + NUM_FINE;                  // 50000
  u32* spk  = (u32*)(wcur + NUM_FINE);         // 600000

  hipMemsetAsync(d_out, 0, (size_t)out_size * sizeof(float), stream);
  hipMemsetAsync(cnt, 0, NUM_FINE * sizeof(int), stream);

  convert_w<<<320, 256, 0, stream>>>(W1, W2, BW1f, BW1c, BW2);
  count_kernel<<<(E_EDGES + 255) / 256, 256, 0, stream>>>(fidx, cnt);
  scan_kernel<<<1, 1024, 0, stream>>>(cnt, wcur);
  scatter_kernel<<<(E_EDGES + 255) / 256, 256, 0, stream>>>(fidx, cidx, wcur, spk);
  precompute_kernel<<<FINE_BLOCKS + COARSE_BLOCKS, 256, 0, stream>>>(
      h_dk, h_si, h_sk, h_di, BW1f, BW1c, b1, Pf, Pc);
  edge_kernel<<<(E_EDGES + 127) / 128, 256, 0, stream>>>(
      Pf, Pc, BW2, h_dk, spk, b2, out);
}

// Round 3
// 280.935 us; speedup vs baseline: 2.4014x; 2.4014x over previous
//
#include <hip/hip_runtime.h>

typedef unsigned short u16;
typedef unsigned int u32;

#define E_EDGES 600000
#define NUM_FINE 50000
#define NUM_COARSE 12500
#define FINE_BLOCKS 391     // ceil(50000/128)
#define COARSE_BLOCKS 98    // ceil(12500/128)
#define CONVERT_BLOCKS 320
#define COUNT_BLOCKS 2344   // ceil(600000/256)
#define SCATTER_BLOCKS 2344

typedef __attribute__((ext_vector_type(8))) short short8;
typedef __attribute__((ext_vector_type(4))) float f32x4;

union Frag { short8 v; u16 s[8]; u32 u[4]; uint4 q; };

__device__ __forceinline__ u32 rne_bf16(float f) {
  union { float f; u32 u; } v; v.f = f;
  return (v.u + 0x7FFFu + ((v.u >> 16) & 1u)) >> 16;
}
__device__ __forceinline__ float bf2f(u32 bits16) {
  union { u32 u; float f; } v; v.u = bits16 << 16; return v.f;
}
__device__ __forceinline__ u32 addrelu_pack(u32 a, u32 b) {
  float lo = fmaxf(bf2f(a & 0xFFFFu) + bf2f(b & 0xFFFFu), 0.0f);
  float hi = fmaxf(bf2f(a >> 16) + bf2f(b >> 16), 0.0f);
  return rne_bf16(lo) | (rne_bf16(hi) << 16);
}

// ---------------------------------------------------------------------------
// prep1: [0,320) convert W1/W2 to fragment-ordered bf16; [320,...) count fidx.
// Fragment layout: [ks][nt][lane][j], value = W[k=ks*32+(lane>>4)*8+j][n=nt*16+(lane&15)]
// ---------------------------------------------------------------------------
__global__ void prep1(const float* __restrict__ W1, const float* __restrict__ W2,
                      u16* __restrict__ BW1f, u16* __restrict__ BW1c,
                      u16* __restrict__ BW2,
                      const int* __restrict__ fidx, int* __restrict__ cnt) {
  if (blockIdx.x < CONVERT_BLOCKS) {
    int o = blockIdx.x * 256 + threadIdx.x;
    if (o >= 81920) return;
    int which = (o < 32768) ? 0 : (o < 65536 ? 1 : 2);
    int idx = (which == 2) ? (o - 65536) : (o & 32767);
    int j = idx & 7, lane = (idx >> 3) & 63, nt = (idx >> 9) & 7, ks = idx >> 12;
    int k = ks * 32 + (lane >> 4) * 8 + j;
    int n = nt * 16 + (lane & 15);
    float v;
    if (which == 2) v = W2[k * 128 + n];
    else {
      int row;
      if (which == 0) row = (k < 128) ? k : (256 + (k - 128));          // si | di
      else            row = (k < 128) ? (128 + k) : (384 + (k - 128));  // sk | dk
      v = W1[row * 128 + n];
    }
    u16 b = (u16)rne_bf16(v);
    if (which == 0) BW1f[idx] = b; else if (which == 1) BW1c[idx] = b; else BW2[idx] = b;
  } else {
    int e = (blockIdx.x - CONVERT_BLOCKS) * 256 + threadIdx.x;
    if (e < E_EDGES) atomicAdd(&cnt[fidx[e]], 1);
  }
}

// ---------------------------------------------------------------------------
// scan: exclusive prefix over cnt[50000] -> wcur, 4 elems/thread
// ---------------------------------------------------------------------------
__global__ void scan_kernel(const int* __restrict__ cnt, int* __restrict__ wcur) {
  __shared__ int wsum[16], woff[16];
  __shared__ int runningS, chunkTot;
  int tid = threadIdx.x, lane = tid & 63, w = tid >> 6;
  if (tid == 0) runningS = 0;
  __syncthreads();
  for (int base = 0; base < NUM_FINE; base += 4096) {
    int i0 = base + tid * 4;
    int4 c = {0, 0, 0, 0};
    if (i0 < NUM_FINE) c = *(const int4*)(cnt + i0);
    int v = c.x + c.y + c.z + c.w;
    int x = v;
#pragma unroll
    for (int off = 1; off < 64; off <<= 1) {
      int y = __shfl_up(x, off, 64);
      if (lane >= off) x += y;
    }
    if (lane == 63) wsum[w] = x;
    __syncthreads();
    if (tid == 0) {
      int a = 0;
      for (int k = 0; k < 16; ++k) { int t = wsum[k]; woff[k] = a; a += t; }
      chunkTot = a;
    }
    __syncthreads();
    if (i0 < NUM_FINE) {
      int ex = runningS + woff[w] + x - v;
      wcur[i0] = ex; wcur[i0 + 1] = ex + c.x;
      wcur[i0 + 2] = ex + c.x + c.y; wcur[i0 + 3] = ex + c.x + c.y + c.z;
    }
    __syncthreads();
    if (tid == 0) runningS += chunkTot;
    __syncthreads();
  }
}

// ---------------------------------------------------------------------------
// prep2: [0,2344) scatter sorted edge packs; [2344,2344+489) precompute P.
// ---------------------------------------------------------------------------
__global__ __launch_bounds__(256, 2) void prep2(
    const int* __restrict__ fidx, const int* __restrict__ cidx,
    int* __restrict__ wcur, u32* __restrict__ spk,
    const float* __restrict__ h_dk, const float* __restrict__ h_si,
    const float* __restrict__ h_sk, const float* __restrict__ h_di,
    const u16* __restrict__ BW1f, const u16* __restrict__ BW1c,
    const float* __restrict__ b1, u16* __restrict__ Pf, u16* __restrict__ Pc) {
  __shared__ u16 bsh[32768];  // 64 KB (W1-slice fragments)

  if (blockIdx.x < SCATTER_BLOCKS) {
    int e = blockIdx.x * 256 + threadIdx.x;
    if (e < E_EDGES) {
      int fi = fidx[e];
      int p = atomicAdd(&wcur[fi], 1);
      spk[p] = ((u32)fi << 14) | (u32)cidx[e];  // fi<2^16, ci<2^14
    }
    return;
  }

  const int b = blockIdx.x - SCATTER_BLOCKS;
  const bool fine = b < FINE_BLOCKS;
  const int rowStart = fine ? b * 128 : (b - FINE_BLOCKS) * 128;
  const int R = fine ? NUM_FINE : NUM_COARSE;
  const float* __restrict__ X1 = fine ? h_si : h_sk;
  const float* __restrict__ X2 = fine ? h_di : h_dk;
  const u16* __restrict__ BW = fine ? BW1f : BW1c;
  u16* __restrict__ P = fine ? Pf : Pc;

  const int tid = threadIdx.x;
  {  // stage 64 KB of B fragments, coalesced
    uint4* d4 = (uint4*)bsh;
    const uint4* s4 = (const uint4*)BW;
#pragma unroll
    for (int k = 0; k < 16; ++k) d4[k * 256 + tid] = s4[k * 256 + tid];
  }
  __syncthreads();

  const int lane = tid & 63;
  const int w = tid >> 6;
  const int qd = lane >> 4;
  const int ml = lane & 15;

  int rowA[2]; bool vA[2];
#pragma unroll
  for (int mt = 0; mt < 2; ++mt) {
    rowA[mt] = rowStart + w * 32 + mt * 16 + ml;
    vA[mt] = rowA[mt] < R;
  }

  f32x4 acc[2][8];
#pragma unroll
  for (int mt = 0; mt < 2; ++mt)
#pragma unroll
    for (int nt = 0; nt < 8; ++nt) acc[mt][nt] = (f32x4){0.f, 0.f, 0.f, 0.f};

  for (int ks = 0; ks < 8; ++ks) {
    const int k0 = ks * 32 + qd * 8;  // 0..255
    short8 a[2];
#pragma unroll
    for (int mt = 0; mt < 2; ++mt) {
      Frag af;
      if (vA[mt]) {
        const float* src = (k0 < 128) ? (X1 + rowA[mt] * 128 + k0)
                                      : (X2 + rowA[mt] * 128 + (k0 - 128));
        const float4* s4 = (const float4*)src;
        float4 v0 = s4[0], v1 = s4[1];
        af.u[0] = rne_bf16(v0.x) | (rne_bf16(v0.y) << 16);
        af.u[1] = rne_bf16(v0.z) | (rne_bf16(v0.w) << 16);
        af.u[2] = rne_bf16(v1.x) | (rne_bf16(v1.y) << 16);
        af.u[3] = rne_bf16(v1.z) | (rne_bf16(v1.w) << 16);
      } else {
        af.u[0] = af.u[1] = af.u[2] = af.u[3] = 0u;
      }
      a[mt] = af.v;
    }
#pragma unroll
    for (int nt = 0; nt < 8; ++nt) {
      Frag bfr;
      bfr.q = *(const uint4*)&bsh[(((ks * 8 + nt) * 64) + lane) * 8];
      acc[0][nt] = __builtin_amdgcn_mfma_f32_16x16x32_bf16(a[0], bfr.v, acc[0][nt], 0, 0, 0);
      acc[1][nt] = __builtin_amdgcn_mfma_f32_16x16x32_bf16(a[1], bfr.v, acc[1][nt], 0, 0, 0);
    }
  }

  float b1v[8];
#pragma unroll
  for (int nt = 0; nt < 8; ++nt) b1v[nt] = fine ? 0.0f : b1[nt * 16 + ml];

#pragma unroll
  for (int mt = 0; mt < 2; ++mt) {
#pragma unroll
    for (int r = 0; r < 4; ++r) {
      const int row = rowStart + w * 32 + mt * 16 + qd * 4 + r;
      if (row < R) {
#pragma unroll
        for (int nt = 0; nt < 8; ++nt)
          P[row * 128 + nt * 16 + ml] = (u16)rne_bf16(acc[mt][nt][r] + b1v[nt]);
      }
    }
  }
}

// ---------------------------------------------------------------------------
// edge_kernel: 128 SORTED edges/block. W2 staged in LDS (32 KB), K-loop MFMA,
// then the SAME 32 KB is reused as a [128][128] bf16 contribution matrix.
// Segment-sum via plain ds_read (no atomics); global atomics only at block
// boundaries. Handles any segment count (no fallback path needed).
// ---------------------------------------------------------------------------
__global__ __launch_bounds__(256, 4) void edge_kernel(
    const u16* __restrict__ Pf, const u16* __restrict__ Pc,
    const u16* __restrict__ BW2, const float* __restrict__ hdk,
    const u32* __restrict__ spk, const float* __restrict__ b2,
    float* __restrict__ out) {
  __shared__ u16 smem[16384];  // 32 KB: W2 frags, then contrib[128][128] bf16
  __shared__ int sh_fi[128], sh_ci[128], sh_segstart[130];
  __shared__ int shS, shHead, shTail, shW0tot;

  const int tid = threadIdx.x;
  const int eb = blockIdx.x * 128;
  const int V = min(128, E_EDGES - eb);

  {  // stage W2 fragments (32 KB), coalesced
    uint4* d4 = (uint4*)smem;
    const uint4* s4 = (const uint4*)BW2;
#pragma unroll
    for (int k = 0; k < 8; ++k) d4[k * 256 + tid] = s4[k * 256 + tid];
  }
  if (tid < 128) {
    if (tid < V) {
      u32 p = spk[eb + tid];
      sh_fi[tid] = (int)(p >> 14);
      sh_ci[tid] = (int)(p & 16383u);
    } else { sh_fi[tid] = -1; sh_ci[tid] = 0; }
  }
  if (tid == 0) {
    shHead = (eb > 0) ? (int)(spk[eb - 1] >> 14) : -1;
    shTail = (eb + V < E_EDGES) ? (int)(spk[eb + V] >> 14) : -1;
  }
  __syncthreads();

  // segment scan over the 128 rows (waves 0-1)
  int f = 0, x = 0;
  if (tid < 128) {
    f = (tid < V) ? ((tid == 0) ? 1 : (sh_fi[tid] != sh_fi[tid - 1] ? 1 : 0)) : 0;
    x = f;
#pragma unroll
    for (int off = 1; off < 64; off <<= 1) {
      int y = __shfl_up(x, off, 64);
      if ((tid & 63) >= off) x += y;
    }
  }
  if (tid == 63) shW0tot = x;
  __syncthreads();
  if (tid >= 64 && tid < 128) x += shW0tot;
  if (tid < V) {
    if (f) sh_segstart[x - 1] = tid;
    if (tid == V - 1) { shS = x; sh_segstart[x] = V; }
  }
  __syncthreads();

  const int lane = tid & 63;
  const int w = tid >> 6;
  const int qd = lane >> 4;
  const int ml = lane & 15;

  int fiA[2], ciA[2]; bool vA[2];
#pragma unroll
  for (int mt = 0; mt < 2; ++mt) {
    const int lr = w * 32 + mt * 16 + ml;
    vA[mt] = lr < V;
    fiA[mt] = vA[mt] ? sh_fi[lr] : 0;
    ciA[mt] = vA[mt] ? sh_ci[lr] : 0;
  }

  f32x4 acc[2][8];
#pragma unroll
  for (int mt = 0; mt < 2; ++mt)
#pragma unroll
    for (int nt = 0; nt < 8; ++nt) acc[mt][nt] = (f32x4){0.f, 0.f, 0.f, 0.f};

  for (int ks = 0; ks < 4; ++ks) {
    const int k0 = ks * 32 + qd * 8;
    short8 a[2];
#pragma unroll
    for (int mt = 0; mt < 2; ++mt) {
      Frag af;
      if (vA[mt]) {
        uint4 pf = *(const uint4*)(Pf + fiA[mt] * 128 + k0);
        uint4 pc = *(const uint4*)(Pc + ciA[mt] * 128 + k0);
        af.u[0] = addrelu_pack(pf.x, pc.x);
        af.u[1] = addrelu_pack(pf.y, pc.y);
        af.u[2] = addrelu_pack(pf.z, pc.z);
        af.u[3] = addrelu_pack(pf.w, pc.w);
      } else {
        af.u[0] = af.u[1] = af.u[2] = af.u[3] = 0u;
      }
      a[mt] = af.v;
    }
#pragma unroll
    for (int nt = 0; nt < 8; ++nt) {
      Frag bfr;
      bfr.q = *(const uint4*)&smem[(((ks * 8 + nt) * 64) + lane) * 8];
      acc[0][nt] = __builtin_amdgcn_mfma_f32_16x16x32_bf16(a[0], bfr.v, acc[0][nt], 0, 0, 0);
      acc[1][nt] = __builtin_amdgcn_mfma_f32_16x16x32_bf16(a[1], bfr.v, acc[1][nt], 0, 0, 0);
    }
  }
  __syncthreads();  // all W2 LDS reads done; smem is now the contrib matrix

  float b2v[8];
#pragma unroll
  for (int nt = 0; nt < 8; ++nt) b2v[nt] = b2[nt * 16 + ml];

#pragma unroll
  for (int mt = 0; mt < 2; ++mt) {
#pragma unroll
    for (int r = 0; r < 4; ++r) {
      const int lr = w * 32 + mt * 16 + qd * 4 + r;
      if (lr < V) {
        const float* __restrict__ hrow = hdk + sh_ci[lr] * 128;
#pragma unroll
        for (int nt = 0; nt < 8; ++nt) {
          const int col = nt * 16 + ml;
          const float psi = fmaxf(acc[mt][nt][r] + b2v[nt], 0.0f);
          smem[lr * 128 + col] = (u16)rne_bf16(psi * hrow[col]);
        }
      }
    }
  }
  __syncthreads();

  // segment reduce: thread owns (segment, col-pair); plain LDS reads, one
  // store (or boundary atomic) per output element.
  const int S = shS;
  for (int idx = tid; idx < S * 64; idx += 256) {
    const int s = idx >> 6, cp = idx & 63;
    const int r0 = sh_segstart[s], r1 = sh_segstart[s + 1];
    float a0 = 0.f, a1 = 0.f;
    for (int r = r0; r < r1; ++r) {
      const u32 v = *(const u32*)&smem[r * 128 + cp * 2];
      a0 += bf2f(v & 0xFFFFu);
      a1 += bf2f(v >> 16);
    }
    const int fi = sh_fi[r0];
    float* op = out + (size_t)fi * 128 + cp * 2;
    const bool at = (s == 0 && shHead == fi) || (s == S - 1 && shTail == fi);
    if (at) { atomicAdd(op, a0); atomicAdd(op + 1, a1); }
    else { op[0] = a0; op[1] = a1; }
  }
}

extern "C" void kernel_launch(void* const* d_in, const int* in_sizes, int n_in,
                              void* d_out, int out_size, void* d_ws, size_t ws_size,
                              hipStream_t stream) {
  const float* h_dk = (const float*)d_in[0];
  const float* h_si = (const float*)d_in[1];
  const float* h_sk = (const float*)d_in[2];
  const float* h_di = (const float*)d_in[3];
  const int* fidx = (const int*)d_in[4];
  const int* cidx = (const int*)d_in[5];
  const float* W1 = (const float*)d_in[6];
  const float* b1 = (const float*)d_in[7];
  const float* W2 = (const float*)d_in[8];
  const float* b2 = (const float*)d_in[9];
  float* out = (float*)d_out;

  u16* Pf   = (u16*)d_ws;                      // 50000*128 bf16
  u16* Pc   = Pf + (size_t)NUM_FINE * 128;     // 12500*128 bf16
  u16* BW1f = Pc + (size_t)NUM_COARSE * 128;   // 32768
  u16* BW1c = BW1f + 32768;                    // 32768
  u16* BW2  = BW1c + 32768;                    // 16384
  int* cnt  = (int*)(BW2 + 16384);             // 50000
  int* wcur = cnt + NUM_FINE;                  // 50000
  u32* spk  = (u32*)(wcur + NUM_FINE);         // 600000

  hipMemsetAsync(d_out, 0, (size_t)out_size * sizeof(float), stream);
  hipMemsetAsync(cnt, 0, NUM_FINE * sizeof(int), stream);

  prep1<<<CONVERT_BLOCKS + COUNT_BLOCKS, 256, 0, stream>>>(
      W1, W2, BW1f, BW1c, BW2, fidx, cnt);
  scan_kernel<<<1, 1024, 0, stream>>>(cnt, wcur);
  prep2<<<SCATTER_BLOCKS + FINE_BLOCKS + COARSE_BLOCKS, 256, 0, stream>>>(
      fidx, cidx, wcur, spk, h_dk, h_si, h_sk, h_di, BW1f, BW1c, b1, Pf, Pc);
  edge_kernel<<<(E_EDGES + 127) / 128, 256, 0, stream>>>(
      Pf, Pc, BW2, h_dk, spk, b2, out);
}